// Round 11
// baseline (288.916 us; speedup 1.0000x reference)
//
#include <hip/hip_runtime.h>
#include <cstdint>
#include <cstddef>

#define TT 8

#define H1_ELEMS (128*32*20*20)   // 1,638,400
#define E2_ELEMS (128*64*81)      // 663,552
#define E3_ELEMS (128*64*49)      // 401,408

typedef __attribute__((ext_vector_type(8))) short short8;
typedef __attribute__((ext_vector_type(4))) float f32x4;

// ---------------- conv1 weight prep: [ochalf][pos][16oc] ----------------
__global__ void prep_wT1(const float* __restrict__ w1, float* __restrict__ wT1) {
  int i = blockIdx.x * 256 + threadIdx.x;           // 32 oc x 256 pos
  if (i >= 8192) return;
  int oc = i >> 8, pos = i & 255;
  wT1[(oc >> 4) * 4096 + pos * 16 + (oc & 15)] = w1[oc * 256 + pos];
}

// ---------------- conv2 MFMA weight prep: fp32 -> exact 3x bf16 frag layout ----
__global__ void prep_w2frag(const float* __restrict__ w2, __bf16* __restrict__ wf) {
  int i = blockIdx.x * 256 + threadIdx.x;
  if (i >= 98304) return;
  int j    = i & 7;
  int oc   = (i >> 3) & 63;
  int quad = (i >> 9) & 3;
  int ksg  = (i >> 11) & 15;
  int term = i >> 15;
  int k = ksg * 32 + quad * 8 + j;
  int ci = k >> 4, kpos = k & 15;
  float w = w2[oc * 512 + ci * 16 + kpos];
  float hf = (float)(__bf16)w;                      // exact 3-term split
  float r1 = w - hf;
  float mf = (float)(__bf16)r1;
  float r2 = r1 - mf;
  __bf16 val = (term == 0) ? (__bf16)w : (term == 1) ? (__bf16)r1 : (__bf16)r2;
  wf[i] = val;
}

// ---------------- conv3 MFMA weight prep: pos-major K = pos*64 + ci (K=576) ----
__global__ void prep_w3frag(const float* __restrict__ w3, __bf16* __restrict__ wf) {
  int i = blockIdx.x * 256 + threadIdx.x;
  if (i >= 110592) return;
  int j    = i & 7;
  int oc   = (i >> 3) & 63;
  int quad = (i >> 9) & 3;
  int tk   = i >> 11;                               // term*18 + kstep
  int term = tk / 18, kstep = tk % 18;
  int k = kstep * 32 + quad * 8 + j;
  int pos = k >> 6, ci = k & 63;
  float w = w3[oc * 576 + ci * 9 + pos];
  float hf = (float)(__bf16)w;
  float r1 = w - hf;
  float mf = (float)(__bf16)r1;
  float r2 = r1 - mf;
  __bf16 val = (term == 0) ? (__bf16)w : (term == 1) ? (__bf16)r1 : (__bf16)r2;
  wf[i] = val;
}

// ---------------- fc1 MFMA weight prep: K' = pos*64 + ci (K=3136, 98 ksteps) ----
// short8 group idx = ((term*98 + s)*4 + quad)*512 + oc ; elem j -> k = s*32+quad*8+j
__global__ void prep_wff(const float* __restrict__ w, __bf16* __restrict__ wf) {
  int i = blockIdx.x * 256 + threadIdx.x;           // 602,112 short8 groups
  if (i >= 602112) return;
  int oc   = i & 511;
  int quad = (i >> 9) & 3;
  int ts   = i >> 11;                               // term*98 + s
  int term = ts / 98, s = ts - term * 98;
  int kbase = s * 32 + quad * 8;
  int pos = kbase >> 6;
  int ci0 = kbase & 63;                             // 8 | 64 so j-run stays in one pos
  union { __bf16 h[8]; short8 v; } V;
  #pragma unroll
  for (int j = 0; j < 8; j++) {
    float wv = w[(size_t)oc * 3136 + (ci0 + j) * 49 + pos];
    float hf = (float)(__bf16)wv;                   // exact 3-term split
    float r1 = wv - hf;
    float mf = (float)(__bf16)r1;
    float r2 = r1 - mf;
    V.h[j] = (term == 0) ? (__bf16)wv : (term == 1) ? (__bf16)r1 : (__bf16)r2;
  }
  *(short8*)(wf + (size_t)i * 8) = V.v;
}

// ---------------- conv1: [128,4,84,84] -> [128,32,20,20], k8 s4 ----------------
__global__ __launch_bounds__(128) void k_conv1(const float* __restrict__ x,
                                               const float* __restrict__ wT,
                                               const float* __restrict__ bias,
                                               float* __restrict__ out) {
  __shared__ float xt[8064];                        // 32,256 B
  int tid = threadIdx.x;
  int img = blockIdx.x >> 2;
  int q   = blockIdx.x & 3;
  int och = blockIdx.y;
  float4* dst = (float4*)xt;
  #pragma unroll
  for (int ci = 0; ci < 4; ci++) {
    const float4* s4 = (const float4*)(x + (size_t)img * 28224 + ci * 7056 + q * 1680);
    for (int i = tid; i < 504; i += 128) dst[ci * 504 + i] = s4[i];
  }
  __syncthreads();
  if (tid >= 100) return;
  int oyl = tid / 20, ox = tid % 20;
  float acc[16];
  #pragma unroll
  for (int j = 0; j < 16; j++) acc[j] = 0.f;
  int xb0 = oyl * 336 + ox * 4;
  const float* wh = wT + och * 4096;
  #pragma unroll 1
  for (int ci = 0; ci < 4; ci++) {
    #pragma unroll 1
    for (int ky = 0; ky < 8; ky++) {
      const float* xr = xt + ci * 2016 + xb0 + ky * 84;
      float4 xa  = *(const float4*)xr;
      float4 xbv = *(const float4*)(xr + 4);
      const float* wr = wh + (ci * 8 + ky) * 128;   // wave-uniform -> s_load
      float xs[8] = {xa.x, xa.y, xa.z, xa.w, xbv.x, xbv.y, xbv.z, xbv.w};
      #pragma unroll
      for (int kx = 0; kx < 8; kx++) {
        #pragma unroll
        for (int j = 0; j < 16; j++)
          acc[j] = fmaf(xs[kx], wr[kx * 16 + j], acc[j]);
      }
    }
  }
  size_t obase = (size_t)img * 12800 + och * 6400 + (q * 5 + oyl) * 20 + ox;
  #pragma unroll
  for (int j = 0; j < 16; j++) out[obase + j * 400] = acc[j] + bias[och * 16 + j];
}

// ---------------- BN stats, two-stage ----------------
template <int HW>
__global__ void k_bnpartial(const float* __restrict__ xp, int C, int Nper,
                            float* __restrict__ pout) {
  int c = blockIdx.x, s = blockIdx.y, S = gridDim.y, tid = threadIdx.x;
  int n = Nper * HW;
  float sum = 0.f, sum2 = 0.f;
  for (int i = tid; i < n; i += 256) {
    int nb = s * Nper + i / HW;
    int p  = i % HW;
    float v = xp[((size_t)nb * C + c) * HW + p];
    sum += v; sum2 += v * v;
  }
  __shared__ float l0[256], l1[256];
  l0[tid] = sum; l1[tid] = sum2; __syncthreads();
  for (int k = 128; k > 0; k >>= 1) {
    if (tid < k) { l0[tid] += l0[tid + k]; l1[tid] += l1[tid + k]; }
    __syncthreads();
  }
  if (tid == 0) { pout[(c * S + s) * 2] = l0[0]; pout[(c * S + s) * 2 + 1] = l1[0]; }
}

__global__ void k_bnfinal(const float* __restrict__ pin, int S, float n,
                          float* __restrict__ meanArr, float* __restrict__ rstdArr) {
  int c = blockIdx.x, lane = threadIdx.x;
  float s = 0.f, s2 = 0.f;
  if (lane < S) { s = pin[(c * S + lane) * 2]; s2 = pin[(c * S + lane) * 2 + 1]; }
  for (int off = 8; off > 0; off >>= 1) { s += __shfl_down(s, off); s2 += __shfl_down(s2, off); }
  if (lane == 0) {
    float m = s / n;
    float var = s2 / n - m * m;
    meanArr[c] = m;
    rstdArr[c] = rsqrtf(var + 1e-5f);
  }
}

// ---------------- BN + LIF stage 1 -> bit-packed spikes ----------------
__global__ void k_lif1b(const float* __restrict__ h, const float* __restrict__ mean,
                        const float* __restrict__ rstd, const float* __restrict__ g,
                        const float* __restrict__ bb, uint32_t* __restrict__ sout) {
  int idx = blockIdx.x * 256 + threadIdx.x;         // < 81920 = (img*32+ci)*20+row
  int ic = idx / 20;
  int ci = ic & 31;
  const float* hp = h + (size_t)idx * 20;
  float gm = g[ci], mm = mean[ci], rs = rstd[ci], bc = bb[ci];
  float xv[20];
  #pragma unroll
  for (int j4 = 0; j4 < 5; j4++) {
    float4 hv = ((const float4*)hp)[j4];
    xv[j4 * 4 + 0] = gm * (hv.x - mm) * rs + bc;
    xv[j4 * 4 + 1] = gm * (hv.y - mm) * rs + bc;
    xv[j4 * 4 + 2] = gm * (hv.z - mm) * rs + bc;
    xv[j4 * 4 + 3] = gm * (hv.w - mm) * rs + bc;
  }
  float v[20];
  #pragma unroll
  for (int j = 0; j < 20; j++) v[j] = 0.f;
  #pragma unroll
  for (int t = 0; t < TT; t++) {
    uint32_t w = 0;
    #pragma unroll
    for (int j = 0; j < 20; j++) {
      v[j] = v[j] + (xv[j] - v[j]) * 0.5f;
      uint32_t s = (v[j] >= 1.0f);
      w |= s << j;
      if (s) v[j] = 0.f;
    }
    sout[t * 81920 + idx] = w;
  }
}

// ---------------- BN + LIF generic -> bit-packed (x differs per t) ----------------
template <int W, int NROW>
__global__ void k_lifb(const float* __restrict__ h, const float* __restrict__ mean,
                       const float* __restrict__ rstd, const float* __restrict__ g,
                       const float* __restrict__ bb, uint32_t* __restrict__ sout,
                       int E) {
  int idx = blockIdx.x * 256 + threadIdx.x;
  int bc = idx / NROW;
  int c = bc & 63;
  float gm = g[c], mm = mean[c], rs = rstd[c], bcn = bb[c];
  float v[W];
  #pragma unroll
  for (int j = 0; j < W; j++) v[j] = 0.f;
  int nword = 128 * 64 * NROW;
  #pragma unroll
  for (int t = 0; t < TT; t++) {
    const float* hp = h + (size_t)t * E + (size_t)idx * W;
    uint32_t w = 0;
    #pragma unroll
    for (int j = 0; j < W; j++) {
      float xv = gm * (hp[j] - mm) * rs + bcn;
      v[j] = v[j] + (xv - v[j]) * 0.5f;
      uint32_t s = (v[j] >= 1.0f);
      w |= s << j;
      if (s) v[j] = 0.f;
    }
    sout[t * nword + idx] = w;
  }
}

// ---------------- conv2 via MFMA: C[96px][64oc] = S[96][512] x W[512][64] per img ----
__global__ __launch_bounds__(256) void k_conv2m(const uint32_t* __restrict__ s1b,
                                                const __bf16* __restrict__ wf,
                                                const float* __restrict__ bias,
                                                float* __restrict__ out) {
  __shared__ uint32_t sp[1280];                     // 2 img x 640 spike words
  __shared__ uint4 wl4[3072];                       // 49,152 B weight chunk
  __bf16* wl = (__bf16*)wl4;
  int tid = threadIdx.x;
  int img0 = blockIdx.x * 2;
  {
    const uint32_t* src = s1b + (size_t)img0 * 640;
    for (int i = tid; i < 1280; i += 256) sp[i] = src[i];
  }
  int wave = tid >> 6, lane = tid & 63;
  int img_local = wave >> 1;
  int tg = wave & 1;
  int l15 = lane & 15, quad = lane >> 4;
  int ci_off = quad >> 1;
  int kyp = (quad & 1) * 2;
  int spb[3], sh[3];
  #pragma unroll
  for (int mt = 0; mt < 3; mt++) {
    int px = tg * 48 + mt * 16 + l15;
    if (px > 80) px = 80;
    int oy = px / 9, ox = px - oy * 9;
    sh[mt]  = ox * 2;
    spb[mt] = img_local * 640 + ci_off * 20 + oy * 2 + kyp;
  }
  f32x4 acc[3][4];
  #pragma unroll
  for (int mt = 0; mt < 3; mt++)
    #pragma unroll
    for (int nt = 0; nt < 4; nt++) acc[mt][nt] = (f32x4){0.f, 0.f, 0.f, 0.f};

  for (int kc = 0; kc < 4; kc++) {
    __syncthreads();
    for (int o = tid * 8; o < 24576; o += 2048) {
      int tk = o >> 11;
      int term = tk >> 2, ksl = tk & 3;
      const __bf16* src = wf + (((term * 16 + kc * 4 + ksl)) << 11) + (o & 2047);
      *(uint4*)(wl + o) = *(const uint4*)src;
    }
    __syncthreads();
    #pragma unroll
    for (int ks = 0; ks < 4; ks++) {
      int ksg = kc * 4 + ks;
      short8 a[3];
      #pragma unroll
      for (int mt = 0; mt < 3; mt++) {
        uint32_t w0 = sp[spb[mt] + ksg * 40];
        uint32_t w1 = sp[spb[mt] + ksg * 40 + 1];
        uint32_t n0 = (w0 >> sh[mt]) & 15u;
        uint32_t n1 = (w1 >> sh[mt]) & 15u;
        union { uint32_t u[4]; short8 v; } A;
        A.u[0] = ((n0 & 1u) ? 0x3F80u : 0u) | ((n0 & 2u) ? 0x3F800000u : 0u);
        A.u[1] = ((n0 & 4u) ? 0x3F80u : 0u) | ((n0 & 8u) ? 0x3F800000u : 0u);
        A.u[2] = ((n1 & 1u) ? 0x3F80u : 0u) | ((n1 & 2u) ? 0x3F800000u : 0u);
        A.u[3] = ((n1 & 4u) ? 0x3F80u : 0u) | ((n1 & 8u) ? 0x3F800000u : 0u);
        a[mt] = A.v;
      }
      #pragma unroll
      for (int term = 0; term < 3; term++) {
        int fb = ((term * 4 + ks) << 11) + (quad << 9);
        #pragma unroll
        for (int nt = 0; nt < 4; nt++) {
          short8 b = *(const short8*)(wl + fb + ((nt << 4) + l15) * 8);
          #pragma unroll
          for (int mt = 0; mt < 3; mt++)
            acc[mt][nt] = __builtin_amdgcn_mfma_f32_16x16x32_bf16(a[mt], b, acc[mt][nt], 0, 0, 0);
        }
      }
    }
  }
  #pragma unroll
  for (int nt = 0; nt < 4; nt++) {
    int oc = nt * 16 + l15;
    float bv = bias[oc];
    float* op = out + ((size_t)(img0 + img_local) * 64 + oc) * 81;
    #pragma unroll
    for (int mt = 0; mt < 3; mt++) {
      int pxr = tg * 48 + mt * 16 + quad * 4;
      #pragma unroll
      for (int r = 0; r < 4; r++) {
        int px = pxr + r;
        if (px < 81) op[px] = acc[mt][nt][r] + bv;
      }
    }
  }
}

// ---------------- spike repack for conv3: [n][64ch][9row](bit=col) -> [n][9r][9c][2half](bit=ci) ----
__global__ void k_s2T(const uint32_t* __restrict__ sbits, uint32_t* __restrict__ s2T) {
  __shared__ uint32_t sb[576];
  int n = blockIdx.x;
  int t = n >> 7, b = n & 127;
  int tid = threadIdx.x;
  const uint32_t* src = sbits + t * 73728 + b * 576;
  for (int i = tid; i < 576; i += 256) sb[i] = src[i];
  __syncthreads();
  if (tid >= 162) return;
  int half = tid & 1, pc = tid >> 1;                // pc = r*9 + col
  int r = pc / 9, cpix = pc - r * 9;
  uint32_t w = 0;
  #pragma unroll
  for (int ci = 0; ci < 32; ci++)
    w |= (((sb[(half * 32 + ci) * 9 + r] >> cpix) & 1u) << ci);
  s2T[(size_t)n * 162 + pc * 2 + half] = w;
}

// ---------------- conv3 via MFMA: C[49px][64oc] = S[49][576] x W[576][64] per img ----
__global__ __launch_bounds__(256) void k_conv3m(const uint32_t* __restrict__ s2T,
                                                const __bf16* __restrict__ wf,
                                                const float* __restrict__ bias,
                                                float* __restrict__ out) {
  __shared__ uint32_t sp[324];                      // 2 img x 162 words
  __shared__ uint4 wl4[4608];                       // 73,728 B weight chunk
  __bf16* wl = (__bf16*)wl4;
  int tid = threadIdx.x;
  int img0 = blockIdx.x * 2;
  {
    const uint32_t* src = s2T + (size_t)img0 * 162;
    for (int i = tid; i < 324; i += 256) sp[i] = src[i];
  }
  int wave = tid >> 6, lane = tid & 63;
  int img_local = wave >> 1, tg = wave & 1;
  int l15 = lane & 15, quad = lane >> 4;
  int qsh = quad * 8;
  int base[2];
  #pragma unroll
  for (int mt = 0; mt < 2; mt++) {
    int px = tg * 32 + mt * 16 + l15;
    if (px > 48) px = 48;
    int oy = px / 7, ox = px - oy * 7;
    base[mt] = img_local * 162 + (oy * 9 + ox) * 2;
  }
  f32x4 acc[2][4];
  #pragma unroll
  for (int mt = 0; mt < 2; mt++)
    #pragma unroll
    for (int nt = 0; nt < 4; nt++) acc[mt][nt] = (f32x4){0.f, 0.f, 0.f, 0.f};

  #pragma unroll
  for (int kc = 0; kc < 3; kc++) {
    __syncthreads();
    #pragma unroll
    for (int it = 0; it < 18; it++) {
      const __bf16* s = wf + (((it / 6) * 18 + kc * 6 + (it % 6)) << 11) + tid * 8;
      *(uint4*)(wl + (it << 11) + tid * 8) = *(const uint4*)s;
    }
    __syncthreads();
    #pragma unroll
    for (int ksl = 0; ksl < 6; ksl++) {
      int kstep = kc * 6 + ksl;
      int pos = kstep >> 1, cihalf = kstep & 1;
      int ky = pos / 3, kx = pos % 3;
      short8 a[2];
      #pragma unroll
      for (int mt = 0; mt < 2; mt++) {
        uint32_t word = sp[base[mt] + (ky * 9 + kx) * 2 + cihalf];
        uint32_t byt = (word >> qsh) & 255u;
        union { uint32_t u[4]; short8 v; } A;
        A.u[0] = ((byt & 1u)  ? 0x3F80u : 0u) | ((byt & 2u)   ? 0x3F800000u : 0u);
        A.u[1] = ((byt & 4u)  ? 0x3F80u : 0u) | ((byt & 8u)   ? 0x3F800000u : 0u);
        A.u[2] = ((byt & 16u) ? 0x3F80u : 0u) | ((byt & 32u)  ? 0x3F800000u : 0u);
        A.u[3] = ((byt & 64u) ? 0x3F80u : 0u) | ((byt & 128u) ? 0x3F800000u : 0u);
        a[mt] = A.v;
      }
      #pragma unroll
      for (int term = 0; term < 3; term++) {
        int fb = ((term * 6 + ksl) << 11) + (quad << 9);
        #pragma unroll
        for (int nt = 0; nt < 4; nt++) {
          short8 b = *(const short8*)(wl + fb + ((nt << 4) + l15) * 8);
          #pragma unroll
          for (int mt = 0; mt < 2; mt++)
            acc[mt][nt] = __builtin_amdgcn_mfma_f32_16x16x32_bf16(a[mt], b, acc[mt][nt], 0, 0, 0);
        }
      }
    }
  }
  #pragma unroll
  for (int nt = 0; nt < 4; nt++) {
    int oc = nt * 16 + l15;
    float bv = bias[oc];
    float* op = out + ((size_t)(img0 + img_local) * 64 + oc) * 49;
    #pragma unroll
    for (int mt = 0; mt < 2; mt++) {
      int pxr = tg * 32 + mt * 16 + quad * 4;
      #pragma unroll
      for (int r = 0; r < 4; r++) {
        int px = pxr + r;
        if (px < 49) op[px] = acc[mt][nt][r] + bv;
      }
    }
  }
}

// ---------------- spike repack for fc1: s3bits [t][b][64ch][7py](bit=px) -> s3T[row][98](bit=ci&31) ----
__global__ void k_s3T(const uint32_t* __restrict__ sbits, uint32_t* __restrict__ s3T) {
  __shared__ uint32_t sb[896];
  int r0 = blockIdx.x * 2;                          // 512 blocks, 2 rows each
  int tid = threadIdx.x;
  for (int i = tid; i < 896; i += 256) {
    int rl = i / 448, o = i - rl * 448;
    int row = r0 + rl;
    sb[i] = sbits[(row >> 7) * 57344 + (row & 127) * 448 + o];
  }
  __syncthreads();
  if (tid >= 196) return;
  int rl = tid / 98, k = tid - rl * 98;             // kstep = pos*2 + cihalf
  int pos = k >> 1, half = k & 1;
  int py = pos / 7, px = pos - py * 7;
  const uint32_t* base = sb + rl * 448 + half * 224 + py;
  uint32_t w = 0;
  #pragma unroll
  for (int ci = 0; ci < 32; ci++)
    w |= ((base[ci * 7] >> px) & 1u) << ci;
  s3T[(size_t)(r0 + rl) * 98 + k] = w;
}

// ---------------- fc1 via MFMA: C[1024][512] = S[1024][3136] x W[3136][512] ----
// grid (16 rowblk of 64, 16 ocblk of 32); 4 waves, wave w: ksteps {4i+w}, mt=4, nt=2.
// B read direct from global (wff L2-resident). 4 K-partials -> k_fc1red_lif.
__global__ __launch_bounds__(256) void k_fc1m(const uint32_t* __restrict__ s3T,
                                              const __bf16* __restrict__ wf,
                                              float* __restrict__ part) {
  __shared__ uint32_t aS[6272];                     // 64 rows x 98 ksteps
  int tid = threadIdx.x;
  int row0 = blockIdx.x * 64;
  int oc0  = blockIdx.y * 32;
  {
    const uint32_t* src = s3T + (size_t)row0 * 98;
    for (int i = tid; i < 6272; i += 256) aS[i] = src[i];
  }
  __syncthreads();
  int wave = tid >> 6, lane = tid & 63;
  int l15 = lane & 15, quad = lane >> 4;
  int qsh = quad * 8;
  f32x4 acc[4][2];
  #pragma unroll
  for (int mt = 0; mt < 4; mt++)
    #pragma unroll
    for (int nt = 0; nt < 2; nt++) acc[mt][nt] = (f32x4){0.f, 0.f, 0.f, 0.f};
  int nIter = (wave < 2) ? 25 : 24;
  #pragma unroll 1
  for (int i = 0; i < nIter; i++) {
    int ks = i * 4 + wave;
    short8 a[4];
    #pragma unroll
    for (int mt = 0; mt < 4; mt++) {
      uint32_t word = aS[(mt * 16 + l15) * 98 + ks];
      uint32_t byt = (word >> qsh) & 255u;
      union { uint32_t u[4]; short8 v; } A;
      A.u[0] = ((byt & 1u)  ? 0x3F80u : 0u) | ((byt & 2u)   ? 0x3F800000u : 0u);
      A.u[1] = ((byt & 4u)  ? 0x3F80u : 0u) | ((byt & 8u)   ? 0x3F800000u : 0u);
      A.u[2] = ((byt & 16u) ? 0x3F80u : 0u) | ((byt & 32u)  ? 0x3F800000u : 0u);
      A.u[3] = ((byt & 64u) ? 0x3F80u : 0u) | ((byt & 128u) ? 0x3F800000u : 0u);
      a[mt] = A.v;
    }
    #pragma unroll
    for (int term = 0; term < 3; term++) {
      size_t fb = ((size_t)((term * 98 + ks) * 4 + quad) * 512 + oc0 + l15) * 8;
      #pragma unroll
      for (int nt = 0; nt < 2; nt++) {
        short8 b = *(const short8*)(wf + fb + nt * 128);  // +16 oc
        #pragma unroll
        for (int mt = 0; mt < 4; mt++)
          acc[mt][nt] = __builtin_amdgcn_mfma_f32_16x16x32_bf16(a[mt], b, acc[mt][nt], 0, 0, 0);
      }
    }
  }
  // store per-wave K-partials: part[wave][row][oc]
  #pragma unroll
  for (int mt = 0; mt < 4; mt++) {
    #pragma unroll
    for (int nt = 0; nt < 2; nt++) {
      int oc = oc0 + nt * 16 + l15;
      #pragma unroll
      for (int r = 0; r < 4; r++) {
        int row = row0 + mt * 16 + quad * 4 + r;
        part[(size_t)wave * 524288 + (size_t)row * 512 + oc] = acc[mt][nt][r];
      }
    }
  }
}

// ---------------- fused: 4-way K-partial reduce + bias + LIF -> hid u8 ----------
__global__ void k_fc1red_lif(const float* __restrict__ part, const float* __restrict__ bias,
                             unsigned char* __restrict__ hid) {
  int idx = blockIdx.x * 256 + threadIdx.x;
  float bv = bias[idx & 511];
  float v = 0.f;
  #pragma unroll
  for (int t = 0; t < TT; t++) {
    float a = part[t * 65536 + idx];
    #pragma unroll
    for (int j = 1; j < 4; j++) a += part[(size_t)j * 524288 + t * 65536 + idx];
    a += bv;
    v = v + (a - v) * 0.5f;
    unsigned char s = (v >= 1.0f);
    hid[t * 65536 + idx] = s;
    if (s) v = 0.f;
  }
}

// ---------------- fco + mean over T: [8,128,512](u8) -> [128,2] ----------------
__global__ void k_fco(const unsigned char* __restrict__ hid, const float* __restrict__ w,
                      const float* __restrict__ bias, float* __restrict__ out) {
  int b = blockIdx.x, tid = threadIdx.x;
  float a0 = 0.f, a1 = 0.f;
  for (int t = 0; t < TT; t++) {
    const unsigned char* hrow = hid + ((size_t)t * 128 + b) * 512;
    for (int o = tid; o < 512; o += 256) {
      if (hrow[o]) { a0 += w[o]; a1 += w[512 + o]; }
    }
  }
  __shared__ float l0[256], l1[256];
  l0[tid] = a0; l1[tid] = a1; __syncthreads();
  for (int k = 128; k > 0; k >>= 1) {
    if (tid < k) { l0[tid] += l0[tid + k]; l1[tid] += l1[tid + k]; }
    __syncthreads();
  }
  if (tid == 0) {
    out[b * 2 + 0] = l0[0] * 0.125f + bias[0];
    out[b * 2 + 1] = l1[0] * 0.125f + bias[1];
  }
}

extern "C" void kernel_launch(void* const* d_in, const int* in_sizes, int n_in,
                              void* d_out, int out_size, void* d_ws, size_t ws_size,
                              hipStream_t stream) {
  const float* x    = (const float*)d_in[0];
  const float* c1w  = (const float*)d_in[1];
  const float* c1b  = (const float*)d_in[2];
  const float* bn1g = (const float*)d_in[3];
  const float* bn1b = (const float*)d_in[4];
  const float* c2w  = (const float*)d_in[5];
  const float* c2b  = (const float*)d_in[6];
  const float* bn2g = (const float*)d_in[7];
  const float* bn2b = (const float*)d_in[8];
  const float* c3w  = (const float*)d_in[9];
  const float* c3b  = (const float*)d_in[10];
  const float* bn3g = (const float*)d_in[11];
  const float* bn3b = (const float*)d_in[12];
  const float* fc1w = (const float*)d_in[13];
  const float* fc1b = (const float*)d_in[14];
  const float* fcow = (const float*)d_in[15];
  const float* fcob = (const float*)d_in[16];
  float* out = (float*)d_out;

  char* ws = (char*)d_ws;
  // workspace (64.9 MB footprint)
  float*    h1     = (float*)(ws + 0);                 //  6,553,600 (dead after lif1b)
  uint32_t* s1bits = (uint32_t*)(ws + 6553600);        //  2,621,440 (dead after conv2m)
  float*    h2     = (float*)(ws + 19660800);          // 21,233,664 (dead after lif2b)
  uint32_t* s2bits = (uint32_t*)(ws + 40894464);       //  2,359,296 (dead after k_s2T)
  float*    h3     = (float*)(ws + 46202880);          // 12,845,056 (dead after lif3b)
  uint32_t* s3bits = (uint32_t*)(ws + 59047936);       //  1,835,008
  unsigned char* hid = (unsigned char*)(ws + 64356352);//    524,288
  float*    st     = (float*)(ws + 64880640);          //      1,280
  // persistent small weights (gap 60,882,944 .. 62,423,040)
  __bf16*   w2f  = (__bf16*)(ws + 60882944);  // 196,608
  __bf16*   w3f  = (__bf16*)(ws + 61079552);  // 221,184
  uint32_t* s2T  = (uint32_t*)(ws + 61300736);// 663,552 (written after lif2b)
  float*    wT1  = (float*)(ws + 62390272);   // 32,768
  // overlays (lifetimes disjoint):
  float*    bnpart = (float*)(ws + 9437184);  // 8,192 in s1 region, past s1bits end
  __bf16*   wff    = (__bf16*)(ws + 19660800);// 9,633,792 in dead-h2 region (after lif2b)
  float*    f1part = (float*)(ws + 29360128); // 8,388,608 in dead-h2 region (fc1 time)
  uint32_t* s3T    = (uint32_t*)(ws + 43253760); // 401,408 in gap after s2bits

  prep_wT1   <<<32, 256, 0, stream>>>(c1w, wT1);
  prep_w2frag<<<384, 256, 0, stream>>>(c2w, w2f);
  prep_w3frag<<<432, 256, 0, stream>>>(c3w, w3f);
  k_conv1    <<<dim3(512, 2), 128, 0, stream>>>(x, wT1, c1b, h1);
  k_bnpartial<400><<<dim3(32, 16), 256, 0, stream>>>(h1, 32, 8, bnpart);
  k_bnfinal  <<<32, 64, 0, stream>>>(bnpart, 16, 128.f * 400.f, st, st + 32);
  k_lif1b    <<<320, 256, 0, stream>>>(h1, st, st + 32, bn1g, bn1b, s1bits);

  k_conv2m   <<<512, 256, 0, stream>>>(s1bits, w2f, c2b, h2);
  k_bnpartial<81><<<dim3(64, 16), 256, 0, stream>>>(h2, 64, 64, bnpart);
  k_bnfinal  <<<64, 64, 0, stream>>>(bnpart, 16, 1024.f * 81.f, st + 64, st + 128);
  k_lifb<9, 9><<<288, 256, 0, stream>>>(h2, st + 64, st + 128, bn2g, bn2b, s2bits, E2_ELEMS);
  prep_wff   <<<2352, 256, 0, stream>>>(fc1w, wff);        // h2 region now free

  k_s2T      <<<1024, 256, 0, stream>>>(s2bits, s2T);
  k_conv3m   <<<512, 256, 0, stream>>>(s2T, w3f, c3b, h3);
  k_bnpartial<49><<<dim3(64, 16), 256, 0, stream>>>(h3, 64, 64, bnpart);
  k_bnfinal  <<<64, 64, 0, stream>>>(bnpart, 16, 1024.f * 49.f, st + 192, st + 256);
  k_lifb<7, 7><<<224, 256, 0, stream>>>(h3, st + 192, st + 256, bn3g, bn3b, s3bits, E3_ELEMS);

  k_s3T      <<<512, 256, 0, stream>>>(s3bits, s3T);
  k_fc1m     <<<dim3(16, 16), 256, 0, stream>>>(s3T, wff, f1part);
  k_fc1red_lif<<<256, 256, 0, stream>>>(f1part, fc1b, hid);
  k_fco      <<<128, 256, 0, stream>>>(hid, fcow, fcob, out);
}

// Round 12
// 260.769 us; speedup vs baseline: 1.1079x; 1.1079x over previous
//
#include <hip/hip_runtime.h>
#include <cstdint>
#include <cstddef>

#define TT 8

#define E2_ELEMS (128*64*81)      // 663,552
#define E3_ELEMS (128*64*49)      // 401,408

typedef __attribute__((ext_vector_type(8))) short short8;
typedef __attribute__((ext_vector_type(4))) float f32x4;

// ---------------- merged small weight preps: wT1 + w2frag + w3frag ----------------
__global__ void prep_all(const float* __restrict__ w1, const float* __restrict__ w2,
                         const float* __restrict__ w3, float* __restrict__ wT1,
                         __bf16* __restrict__ w2f, __bf16* __restrict__ w3f) {
  int i = blockIdx.x * 256 + threadIdx.x;
  if (i < 8192) {                                   // conv1: [ochalf][pos][16oc]
    int oc = i >> 8, pos = i & 255;
    wT1[(oc >> 4) * 4096 + pos * 16 + (oc & 15)] = w1[oc * 256 + pos];
  } else if (i < 106496) {                          // conv2 frag, exact 3-term split
    int v = i - 8192;
    int j    = v & 7;
    int oc   = (v >> 3) & 63;
    int quad = (v >> 9) & 3;
    int ksg  = (v >> 11) & 15;
    int term = v >> 15;
    int k = ksg * 32 + quad * 8 + j;
    int ci = k >> 4, kpos = k & 15;
    float w = w2[oc * 512 + ci * 16 + kpos];
    float hf = (float)(__bf16)w;
    float r1 = w - hf;
    float mf = (float)(__bf16)r1;
    float r2 = r1 - mf;
    w2f[v] = (term == 0) ? (__bf16)w : (term == 1) ? (__bf16)r1 : (__bf16)r2;
  } else if (i < 217088) {                          // conv3 frag, pos-major K=576
    int v = i - 106496;
    int j    = v & 7;
    int oc   = (v >> 3) & 63;
    int quad = (v >> 9) & 3;
    int tk   = v >> 11;
    int term = tk / 18, kstep = tk % 18;
    int k = kstep * 32 + quad * 8 + j;
    int pos = k >> 6, ci = k & 63;
    float w = w3[oc * 576 + ci * 9 + pos];
    float hf = (float)(__bf16)w;
    float r1 = w - hf;
    float mf = (float)(__bf16)r1;
    float r2 = r1 - mf;
    w3f[v] = (term == 0) ? (__bf16)w : (term == 1) ? (__bf16)r1 : (__bf16)r2;
  }
}

// ---------------- fc1 MFMA weight prep (coalesced tiled): K'=pos*64+ci ----------------
// group idx = ((term*98 + s)*4 + quad)*512 + oc ; elem j -> k' = s*32+quad*8+j
__global__ __launch_bounds__(256) void prep_wff(const float* __restrict__ w,
                                                __bf16* __restrict__ wf) {
  __shared__ float tile[12544];                     // 32 oc x 392 (8ci x 49pos)
  int oc0 = blockIdx.x * 32;                        // 16 octiles
  int ci0 = blockIdx.y * 8;                         // 8 citiles
  int tid = threadIdx.x;
  for (int f = tid; f < 12544; f += 256) {          // coalesced: 392-contig runs
    int oc_l = f / 392, r = f - oc_l * 392;
    tile[f] = w[(size_t)(oc0 + oc_l) * 3136 + ci0 * 49 + r];
  }
  __syncthreads();
  int squad = (ci0 & 31) >> 3;                      // fixed quad for this citile
  int sadd  = ci0 >> 5;
  for (int g = tid; g < 1568; g += 256) {           // 49 pos x 32 oc
    int pos = g >> 5, oc_l = g & 31;
    union { __bf16 h[8]; uint4 u; } T0, T1, T2;
    #pragma unroll
    for (int j = 0; j < 8; j++) {
      float wv = tile[oc_l * 392 + j * 49 + pos];
      float hf = (float)(__bf16)wv;                 // exact 3-term split
      float r1 = wv - hf;
      float mf = (float)(__bf16)r1;
      float r2 = r1 - mf;
      T0.h[j] = (__bf16)wv; T1.h[j] = (__bf16)r1; T2.h[j] = (__bf16)r2;
    }
    int s = pos * 2 + sadd;
    size_t b0 = (((size_t)s * 4 + squad) * 512 + oc0 + oc_l) * 8;
    *(uint4*)(wf + b0)               = T0.u;        // term stride = 98*4*512*8
    *(uint4*)(wf + b0 + 1605632)     = T1.u;
    *(uint4*)(wf + b0 + 3211264)     = T2.u;
  }
}

// ---------------- conv1 + fused BN partial stats ----------------
__global__ __launch_bounds__(128) void k_conv1(const float* __restrict__ x,
                                               const float* __restrict__ wT,
                                               const float* __restrict__ bias,
                                               float* __restrict__ out,
                                               float* __restrict__ pout) {
  __shared__ float xt[8064];                        // 32,256 B (reused for stats)
  int tid = threadIdx.x;
  int img = blockIdx.x >> 2;
  int q   = blockIdx.x & 3;
  int och = blockIdx.y;
  float4* dst = (float4*)xt;
  #pragma unroll
  for (int ci = 0; ci < 4; ci++) {
    const float4* s4 = (const float4*)(x + (size_t)img * 28224 + ci * 7056 + q * 1680);
    for (int i = tid; i < 504; i += 128) dst[ci * 504 + i] = s4[i];
  }
  __syncthreads();
  bool active = tid < 100;
  int oyl = tid / 20, ox = tid % 20;
  float acc[16];
  #pragma unroll
  for (int j = 0; j < 16; j++) acc[j] = 0.f;
  if (active) {
    int xb0 = oyl * 336 + ox * 4;
    const float* wh = wT + och * 4096;
    #pragma unroll 1
    for (int ci = 0; ci < 4; ci++) {
      #pragma unroll 1
      for (int ky = 0; ky < 8; ky++) {
        const float* xr = xt + ci * 2016 + xb0 + ky * 84;
        float4 xa  = *(const float4*)xr;
        float4 xbv = *(const float4*)(xr + 4);
        const float* wr = wh + (ci * 8 + ky) * 128; // wave-uniform -> s_load
        float xs[8] = {xa.x, xa.y, xa.z, xa.w, xbv.x, xbv.y, xbv.z, xbv.w};
        #pragma unroll
        for (int kx = 0; kx < 8; kx++) {
          #pragma unroll
          for (int j = 0; j < 16; j++)
            acc[j] = fmaf(xs[kx], wr[kx * 16 + j], acc[j]);
        }
      }
    }
  }
  __syncthreads();                                  // xt now free for stats
  size_t obase = (size_t)img * 12800 + och * 6400 + (q * 5 + oyl) * 20 + ox;
  #pragma unroll
  for (int j = 0; j < 16; j++) {
    float v = 0.f;
    if (active) {
      v = acc[j] + bias[och * 16 + j];
      out[obase + j * 400] = v;
    }
    xt[j * 128 + tid] = v;
    xt[2048 + j * 128 + tid] = v * v;
  }
  __syncthreads();
  for (int off = 64; off > 0; off >>= 1) {
    if (tid < off) {
      #pragma unroll
      for (int j = 0; j < 16; j++) {
        xt[j * 128 + tid] += xt[j * 128 + tid + off];
        xt[2048 + j * 128 + tid] += xt[2048 + j * 128 + tid + off];
      }
    }
    __syncthreads();
  }
  if (tid < 16) {
    pout[(och * 16 + tid) * 512 + blockIdx.x] = xt[tid * 128];
    pout[16384 + (och * 16 + tid) * 512 + blockIdx.x] = xt[2048 + tid * 128];
  }
}

// ---------------- BN final: reduce 512 partials per channel ----------------
__global__ void k_bnfinal2(const float* __restrict__ pin, int sqoff, float n,
                           float* __restrict__ meanArr, float* __restrict__ rstdArr) {
  __shared__ float l0[256], l1[256];
  int c = blockIdx.x, tid = threadIdx.x;
  l0[tid] = pin[c * 512 + tid] + pin[c * 512 + tid + 256];
  l1[tid] = pin[sqoff + c * 512 + tid] + pin[sqoff + c * 512 + tid + 256];
  __syncthreads();
  for (int k = 128; k > 0; k >>= 1) {
    if (tid < k) { l0[tid] += l0[tid + k]; l1[tid] += l1[tid + k]; }
    __syncthreads();
  }
  if (tid == 0) {
    float m = l0[0] / n;
    float var = l1[0] / n - m * m;
    meanArr[c] = m;
    rstdArr[c] = rsqrtf(var + 1e-5f);
  }
}

// ---------------- BN + LIF stage 1 -> bit-packed spikes ----------------
__global__ void k_lif1b(const float* __restrict__ h, const float* __restrict__ mean,
                        const float* __restrict__ rstd, const float* __restrict__ g,
                        const float* __restrict__ bb, uint32_t* __restrict__ sout) {
  int idx = blockIdx.x * 256 + threadIdx.x;         // < 81920 = (img*32+ci)*20+row
  int ic = idx / 20;
  int ci = ic & 31;
  const float* hp = h + (size_t)idx * 20;
  float gm = g[ci], mm = mean[ci], rs = rstd[ci], bc = bb[ci];
  float xv[20];
  #pragma unroll
  for (int j4 = 0; j4 < 5; j4++) {
    float4 hv = ((const float4*)hp)[j4];
    xv[j4 * 4 + 0] = gm * (hv.x - mm) * rs + bc;
    xv[j4 * 4 + 1] = gm * (hv.y - mm) * rs + bc;
    xv[j4 * 4 + 2] = gm * (hv.z - mm) * rs + bc;
    xv[j4 * 4 + 3] = gm * (hv.w - mm) * rs + bc;
  }
  float v[20];
  #pragma unroll
  for (int j = 0; j < 20; j++) v[j] = 0.f;
  #pragma unroll
  for (int t = 0; t < TT; t++) {
    uint32_t w = 0;
    #pragma unroll
    for (int j = 0; j < 20; j++) {
      v[j] = v[j] + (xv[j] - v[j]) * 0.5f;
      uint32_t s = (v[j] >= 1.0f);
      w |= s << j;
      if (s) v[j] = 0.f;
    }
    sout[t * 81920 + idx] = w;
  }
}

// ---------------- BN + LIF generic -> bit-packed (x differs per t) ----------------
template <int W, int NROW>
__global__ void k_lifb(const float* __restrict__ h, const float* __restrict__ mean,
                       const float* __restrict__ rstd, const float* __restrict__ g,
                       const float* __restrict__ bb, uint32_t* __restrict__ sout,
                       int E) {
  int idx = blockIdx.x * 256 + threadIdx.x;
  int bc = idx / NROW;
  int c = bc & 63;
  float gm = g[c], mm = mean[c], rs = rstd[c], bcn = bb[c];
  float v[W];
  #pragma unroll
  for (int j = 0; j < W; j++) v[j] = 0.f;
  int nword = 128 * 64 * NROW;
  #pragma unroll
  for (int t = 0; t < TT; t++) {
    const float* hp = h + (size_t)t * E + (size_t)idx * W;
    uint32_t w = 0;
    #pragma unroll
    for (int j = 0; j < W; j++) {
      float xv = gm * (hp[j] - mm) * rs + bcn;
      v[j] = v[j] + (xv - v[j]) * 0.5f;
      uint32_t s = (v[j] >= 1.0f);
      w |= s << j;
      if (s) v[j] = 0.f;
    }
    sout[t * nword + idx] = w;
  }
}

// ---------------- conv2 via MFMA + fused BN partial stats ----------------
__global__ __launch_bounds__(256) void k_conv2m(const uint32_t* __restrict__ s1b,
                                                const __bf16* __restrict__ wf,
                                                const float* __restrict__ bias,
                                                float* __restrict__ out,
                                                float* __restrict__ pout) {
  __shared__ uint32_t sp[1280];                     // 2 img x 640 spike words
  __shared__ uint4 wl4[3072];                       // 49,152 B weight chunk (reused)
  __bf16* wl = (__bf16*)wl4;
  int tid = threadIdx.x;
  int img0 = blockIdx.x * 2;
  {
    const uint32_t* src = s1b + (size_t)img0 * 640;
    for (int i = tid; i < 1280; i += 256) sp[i] = src[i];
  }
  int wave = tid >> 6, lane = tid & 63;
  int img_local = wave >> 1;
  int tg = wave & 1;
  int l15 = lane & 15, quad = lane >> 4;
  int ci_off = quad >> 1;
  int kyp = (quad & 1) * 2;
  int spb[3], sh[3];
  #pragma unroll
  for (int mt = 0; mt < 3; mt++) {
    int px = tg * 48 + mt * 16 + l15;
    if (px > 80) px = 80;
    int oy = px / 9, ox = px - oy * 9;
    sh[mt]  = ox * 2;
    spb[mt] = img_local * 640 + ci_off * 20 + oy * 2 + kyp;
  }
  f32x4 acc[3][4];
  #pragma unroll
  for (int mt = 0; mt < 3; mt++)
    #pragma unroll
    for (int nt = 0; nt < 4; nt++) acc[mt][nt] = (f32x4){0.f, 0.f, 0.f, 0.f};

  for (int kc = 0; kc < 4; kc++) {
    __syncthreads();
    for (int o = tid * 8; o < 24576; o += 2048) {
      int tk = o >> 11;
      int term = tk >> 2, ksl = tk & 3;
      const __bf16* src = wf + (((term * 16 + kc * 4 + ksl)) << 11) + (o & 2047);
      *(uint4*)(wl + o) = *(const uint4*)src;
    }
    __syncthreads();
    #pragma unroll
    for (int ks = 0; ks < 4; ks++) {
      int ksg = kc * 4 + ks;
      short8 a[3];
      #pragma unroll
      for (int mt = 0; mt < 3; mt++) {
        uint32_t w0 = sp[spb[mt] + ksg * 40];
        uint32_t w1 = sp[spb[mt] + ksg * 40 + 1];
        uint32_t n0 = (w0 >> sh[mt]) & 15u;
        uint32_t n1 = (w1 >> sh[mt]) & 15u;
        union { uint32_t u[4]; short8 v; } A;
        A.u[0] = ((n0 & 1u) ? 0x3F80u : 0u) | ((n0 & 2u) ? 0x3F800000u : 0u);
        A.u[1] = ((n0 & 4u) ? 0x3F80u : 0u) | ((n0 & 8u) ? 0x3F800000u : 0u);
        A.u[2] = ((n1 & 1u) ? 0x3F80u : 0u) | ((n1 & 2u) ? 0x3F800000u : 0u);
        A.u[3] = ((n1 & 4u) ? 0x3F80u : 0u) | ((n1 & 8u) ? 0x3F800000u : 0u);
        a[mt] = A.v;
      }
      #pragma unroll
      for (int term = 0; term < 3; term++) {
        int fb = ((term * 4 + ks) << 11) + (quad << 9);
        #pragma unroll
        for (int nt = 0; nt < 4; nt++) {
          short8 b = *(const short8*)(wl + fb + ((nt << 4) + l15) * 8);
          #pragma unroll
          for (int mt = 0; mt < 3; mt++)
            acc[mt][nt] = __builtin_amdgcn_mfma_f32_16x16x32_bf16(a[mt], b, acc[mt][nt], 0, 0, 0);
        }
      }
    }
  }
  float sl[4], sl2[4];
  #pragma unroll
  for (int nt = 0; nt < 4; nt++) {
    sl[nt] = 0.f; sl2[nt] = 0.f;
    int oc = nt * 16 + l15;
    float bv = bias[oc];
    float* op = out + ((size_t)(img0 + img_local) * 64 + oc) * 81;
    #pragma unroll
    for (int mt = 0; mt < 3; mt++) {
      int pxr = tg * 48 + mt * 16 + quad * 4;
      #pragma unroll
      for (int r = 0; r < 4; r++) {
        int px = pxr + r;
        if (px < 81) {
          float v = acc[mt][nt][r] + bv;
          op[px] = v;
          sl[nt] += v; sl2[nt] += v * v;
        }
      }
    }
  }
  __syncthreads();                                  // wl region now free for stats
  float* sred = (float*)wl4;                        // [64oc][16] + [64oc][16]
  #pragma unroll
  for (int nt = 0; nt < 4; nt++) {
    int idx = (nt * 16 + l15) * 16 + (wave * 4 + quad);
    sred[idx] = sl[nt];
    sred[1024 + idx] = sl2[nt];
  }
  __syncthreads();
  if (tid < 64) {
    float s = 0.f, s2 = 0.f;
    #pragma unroll
    for (int k = 0; k < 16; k++) { s += sred[tid * 16 + k]; s2 += sred[1024 + tid * 16 + k]; }
    pout[tid * 512 + blockIdx.x] = s;
    pout[32768 + tid * 512 + blockIdx.x] = s2;
  }
}

// ---------------- spike repack for conv3 ----------------
__global__ void k_s2T(const uint32_t* __restrict__ sbits, uint32_t* __restrict__ s2T) {
  __shared__ uint32_t sb[576];
  int n = blockIdx.x;
  int t = n >> 7, b = n & 127;
  int tid = threadIdx.x;
  const uint32_t* src = sbits + t * 73728 + b * 576;
  for (int i = tid; i < 576; i += 256) sb[i] = src[i];
  __syncthreads();
  if (tid >= 162) return;
  int half = tid & 1, pc = tid >> 1;
  int r = pc / 9, cpix = pc - r * 9;
  uint32_t w = 0;
  #pragma unroll
  for (int ci = 0; ci < 32; ci++)
    w |= (((sb[(half * 32 + ci) * 9 + r] >> cpix) & 1u) << ci);
  s2T[(size_t)n * 162 + pc * 2 + half] = w;
}

// ---------------- conv3 via MFMA + fused BN partial stats ----------------
__global__ __launch_bounds__(256) void k_conv3m(const uint32_t* __restrict__ s2T,
                                                const __bf16* __restrict__ wf,
                                                const float* __restrict__ bias,
                                                float* __restrict__ out,
                                                float* __restrict__ pout) {
  __shared__ uint32_t sp[324];
  __shared__ uint4 wl4[4608];                       // 73,728 B (reused for stats)
  __bf16* wl = (__bf16*)wl4;
  int tid = threadIdx.x;
  int img0 = blockIdx.x * 2;
  {
    const uint32_t* src = s2T + (size_t)img0 * 162;
    for (int i = tid; i < 324; i += 256) sp[i] = src[i];
  }
  int wave = tid >> 6, lane = tid & 63;
  int img_local = wave >> 1, tg = wave & 1;
  int l15 = lane & 15, quad = lane >> 4;
  int qsh = quad * 8;
  int base[2];
  #pragma unroll
  for (int mt = 0; mt < 2; mt++) {
    int px = tg * 32 + mt * 16 + l15;
    if (px > 48) px = 48;
    int oy = px / 7, ox = px - oy * 7;
    base[mt] = img_local * 162 + (oy * 9 + ox) * 2;
  }
  f32x4 acc[2][4];
  #pragma unroll
  for (int mt = 0; mt < 2; mt++)
    #pragma unroll
    for (int nt = 0; nt < 4; nt++) acc[mt][nt] = (f32x4){0.f, 0.f, 0.f, 0.f};

  #pragma unroll
  for (int kc = 0; kc < 3; kc++) {
    __syncthreads();
    #pragma unroll
    for (int it = 0; it < 18; it++) {
      const __bf16* s = wf + (((it / 6) * 18 + kc * 6 + (it % 6)) << 11) + tid * 8;
      *(uint4*)(wl + (it << 11) + tid * 8) = *(const uint4*)s;
    }
    __syncthreads();
    #pragma unroll
    for (int ksl = 0; ksl < 6; ksl++) {
      int kstep = kc * 6 + ksl;
      int pos = kstep >> 1, cihalf = kstep & 1;
      int ky = pos / 3, kx = pos % 3;
      short8 a[2];
      #pragma unroll
      for (int mt = 0; mt < 2; mt++) {
        uint32_t word = sp[base[mt] + (ky * 9 + kx) * 2 + cihalf];
        uint32_t byt = (word >> qsh) & 255u;
        union { uint32_t u[4]; short8 v; } A;
        A.u[0] = ((byt & 1u)  ? 0x3F80u : 0u) | ((byt & 2u)   ? 0x3F800000u : 0u);
        A.u[1] = ((byt & 4u)  ? 0x3F80u : 0u) | ((byt & 8u)   ? 0x3F800000u : 0u);
        A.u[2] = ((byt & 16u) ? 0x3F80u : 0u) | ((byt & 32u)  ? 0x3F800000u : 0u);
        A.u[3] = ((byt & 64u) ? 0x3F80u : 0u) | ((byt & 128u) ? 0x3F800000u : 0u);
        a[mt] = A.v;
      }
      #pragma unroll
      for (int term = 0; term < 3; term++) {
        int fb = ((term * 6 + ksl) << 11) + (quad << 9);
        #pragma unroll
        for (int nt = 0; nt < 4; nt++) {
          short8 b = *(const short8*)(wl + fb + ((nt << 4) + l15) * 8);
          #pragma unroll
          for (int mt = 0; mt < 2; mt++)
            acc[mt][nt] = __builtin_amdgcn_mfma_f32_16x16x32_bf16(a[mt], b, acc[mt][nt], 0, 0, 0);
        }
      }
    }
  }
  float sl[4], sl2[4];
  #pragma unroll
  for (int nt = 0; nt < 4; nt++) {
    sl[nt] = 0.f; sl2[nt] = 0.f;
    int oc = nt * 16 + l15;
    float bv = bias[oc];
    float* op = out + ((size_t)(img0 + img_local) * 64 + oc) * 49;
    #pragma unroll
    for (int mt = 0; mt < 2; mt++) {
      int pxr = tg * 32 + mt * 16 + quad * 4;
      #pragma unroll
      for (int r = 0; r < 4; r++) {
        int px = pxr + r;
        if (px < 49) {
          float v = acc[mt][nt][r] + bv;
          op[px] = v;
          sl[nt] += v; sl2[nt] += v * v;
        }
      }
    }
  }
  __syncthreads();
  float* sred = (float*)wl4;
  #pragma unroll
  for (int nt = 0; nt < 4; nt++) {
    int idx = (nt * 16 + l15) * 16 + (wave * 4 + quad);
    sred[idx] = sl[nt];
    sred[1024 + idx] = sl2[nt];
  }
  __syncthreads();
  if (tid < 64) {
    float s = 0.f, s2 = 0.f;
    #pragma unroll
    for (int k = 0; k < 16; k++) { s += sred[tid * 16 + k]; s2 += sred[1024 + tid * 16 + k]; }
    pout[tid * 512 + blockIdx.x] = s;
    pout[32768 + tid * 512 + blockIdx.x] = s2;
  }
}

// ---------------- spike repack for fc1 ----------------
__global__ void k_s3T(const uint32_t* __restrict__ sbits, uint32_t* __restrict__ s3T) {
  __shared__ uint32_t sb[896];
  int r0 = blockIdx.x * 2;
  int tid = threadIdx.x;
  for (int i = tid; i < 896; i += 256) {
    int rl = i / 448, o = i - rl * 448;
    int row = r0 + rl;
    sb[i] = sbits[(row >> 7) * 57344 + (row & 127) * 448 + o];
  }
  __syncthreads();
  if (tid >= 196) return;
  int rl = tid / 98, k = tid - rl * 98;
  int pos = k >> 1, half = k & 1;
  int py = pos / 7, px = pos - py * 7;
  const uint32_t* base = sb + rl * 448 + half * 224 + py;
  uint32_t w = 0;
  #pragma unroll
  for (int ci = 0; ci < 32; ci++)
    w |= ((base[ci * 7] >> px) & 1u) << ci;
  s3T[(size_t)(r0 + rl) * 98 + k] = w;
}

// ---------------- fc1 via MFMA ----------------
__global__ __launch_bounds__(256) void k_fc1m(const uint32_t* __restrict__ s3T,
                                              const __bf16* __restrict__ wf,
                                              float* __restrict__ part) {
  __shared__ uint32_t aS[6272];                     // 64 rows x 98 ksteps
  int tid = threadIdx.x;
  int row0 = blockIdx.x * 64;
  int oc0  = blockIdx.y * 32;
  {
    const uint32_t* src = s3T + (size_t)row0 * 98;
    for (int i = tid; i < 6272; i += 256) aS[i] = src[i];
  }
  __syncthreads();
  int wave = tid >> 6, lane = tid & 63;
  int l15 = lane & 15, quad = lane >> 4;
  int qsh = quad * 8;
  f32x4 acc[4][2];
  #pragma unroll
  for (int mt = 0; mt < 4; mt++)
    #pragma unroll
    for (int nt = 0; nt < 2; nt++) acc[mt][nt] = (f32x4){0.f, 0.f, 0.f, 0.f};
  int nIter = (wave < 2) ? 25 : 24;
  #pragma unroll 1
  for (int i = 0; i < nIter; i++) {
    int ks = i * 4 + wave;
    short8 a[4];
    #pragma unroll
    for (int mt = 0; mt < 4; mt++) {
      uint32_t word = aS[(mt * 16 + l15) * 98 + ks];
      uint32_t byt = (word >> qsh) & 255u;
      union { uint32_t u[4]; short8 v; } A;
      A.u[0] = ((byt & 1u)  ? 0x3F80u : 0u) | ((byt & 2u)   ? 0x3F800000u : 0u);
      A.u[1] = ((byt & 4u)  ? 0x3F80u : 0u) | ((byt & 8u)   ? 0x3F800000u : 0u);
      A.u[2] = ((byt & 16u) ? 0x3F80u : 0u) | ((byt & 32u)  ? 0x3F800000u : 0u);
      A.u[3] = ((byt & 64u) ? 0x3F80u : 0u) | ((byt & 128u) ? 0x3F800000u : 0u);
      a[mt] = A.v;
    }
    #pragma unroll
    for (int term = 0; term < 3; term++) {
      size_t fb = ((size_t)((term * 98 + ks) * 4 + quad) * 512 + oc0 + l15) * 8;
      #pragma unroll
      for (int nt = 0; nt < 2; nt++) {
        short8 b = *(const short8*)(wf + fb + nt * 128);
        #pragma unroll
        for (int mt = 0; mt < 4; mt++)
          acc[mt][nt] = __builtin_amdgcn_mfma_f32_16x16x32_bf16(a[mt], b, acc[mt][nt], 0, 0, 0);
      }
    }
  }
  #pragma unroll
  for (int mt = 0; mt < 4; mt++) {
    #pragma unroll
    for (int nt = 0; nt < 2; nt++) {
      int oc = oc0 + nt * 16 + l15;
      #pragma unroll
      for (int r = 0; r < 4; r++) {
        int row = row0 + mt * 16 + quad * 4 + r;
        part[(size_t)wave * 524288 + (size_t)row * 512 + oc] = acc[mt][nt][r];
      }
    }
  }
}

// ---------------- fused: 4-way K-partial reduce + bias + LIF -> hid u8 ----------
__global__ void k_fc1red_lif(const float* __restrict__ part, const float* __restrict__ bias,
                             unsigned char* __restrict__ hid) {
  int idx = blockIdx.x * 256 + threadIdx.x;
  float bv = bias[idx & 511];
  float v = 0.f;
  #pragma unroll
  for (int t = 0; t < TT; t++) {
    float a = part[t * 65536 + idx];
    #pragma unroll
    for (int j = 1; j < 4; j++) a += part[(size_t)j * 524288 + t * 65536 + idx];
    a += bv;
    v = v + (a - v) * 0.5f;
    unsigned char s = (v >= 1.0f);
    hid[t * 65536 + idx] = s;
    if (s) v = 0.f;
  }
}

// ---------------- fco + mean over T ----------------
__global__ void k_fco(const unsigned char* __restrict__ hid, const float* __restrict__ w,
                      const float* __restrict__ bias, float* __restrict__ out) {
  int b = blockIdx.x, tid = threadIdx.x;
  float a0 = 0.f, a1 = 0.f;
  for (int t = 0; t < TT; t++) {
    const unsigned char* hrow = hid + ((size_t)t * 128 + b) * 512;
    for (int o = tid; o < 512; o += 256) {
      if (hrow[o]) { a0 += w[o]; a1 += w[512 + o]; }
    }
  }
  __shared__ float l0[256], l1[256];
  l0[tid] = a0; l1[tid] = a1; __syncthreads();
  for (int k = 128; k > 0; k >>= 1) {
    if (tid < k) { l0[tid] += l0[tid + k]; l1[tid] += l1[tid + k]; }
    __syncthreads();
  }
  if (tid == 0) {
    out[b * 2 + 0] = l0[0] * 0.125f + bias[0];
    out[b * 2 + 1] = l1[0] * 0.125f + bias[1];
  }
}

extern "C" void kernel_launch(void* const* d_in, const int* in_sizes, int n_in,
                              void* d_out, int out_size, void* d_ws, size_t ws_size,
                              hipStream_t stream) {
  const float* x    = (const float*)d_in[0];
  const float* c1w  = (const float*)d_in[1];
  const float* c1b  = (const float*)d_in[2];
  const float* bn1g = (const float*)d_in[3];
  const float* bn1b = (const float*)d_in[4];
  const float* c2w  = (const float*)d_in[5];
  const float* c2b  = (const float*)d_in[6];
  const float* bn2g = (const float*)d_in[7];
  const float* bn2b = (const float*)d_in[8];
  const float* c3w  = (const float*)d_in[9];
  const float* c3b  = (const float*)d_in[10];
  const float* bn3g = (const float*)d_in[11];
  const float* bn3b = (const float*)d_in[12];
  const float* fc1w = (const float*)d_in[13];
  const float* fc1b = (const float*)d_in[14];
  const float* fcow = (const float*)d_in[15];
  const float* fcob = (const float*)d_in[16];
  float* out = (float*)d_out;

  char* ws = (char*)d_ws;
  // workspace (64.9 MB footprint)
  float*    h1     = (float*)(ws + 0);                 //  6,553,600 (dead after lif1b)
  uint32_t* s1bits = (uint32_t*)(ws + 6553600);        //  2,621,440 (dead after conv2m)
  float*    h2     = (float*)(ws + 19660800);          // 21,233,664 (dead after lif2b)
  uint32_t* s2bits = (uint32_t*)(ws + 40894464);       //  2,359,296 (dead after k_s2T)
  float*    h3     = (float*)(ws + 46202880);          // 12,845,056 (dead after lif3b)
  uint32_t* s3bits = (uint32_t*)(ws + 59047936);       //  1,835,008
  unsigned char* hid = (unsigned char*)(ws + 64356352);//    524,288
  float*    st     = (float*)(ws + 64880640);          //      1,280
  // persistent small weights (gap 60,882,944 .. 62,423,040)
  __bf16*   w2f  = (__bf16*)(ws + 60882944);  // 196,608
  __bf16*   w3f  = (__bf16*)(ws + 61079552);  // 221,184
  uint32_t* s2T  = (uint32_t*)(ws + 61300736);// 663,552 (written after lif2b)
  float*    wT1  = (float*)(ws + 62390272);   // 32,768
  // overlays (lifetimes disjoint):
  float*    bnpart = (float*)(ws + 9437184);  // 262,144 in s1 region, past s1bits end
  __bf16*   wff    = (__bf16*)(ws + 19660800);// 9,633,792 in dead-h2 region (after lif2b)
  float*    f1part = (float*)(ws + 29360128); // 8,388,608 in dead-h2 region (fc1 time)
  uint32_t* s3T    = (uint32_t*)(ws + 43253760); // 401,408 in gap after s2bits

  prep_all   <<<848, 256, 0, stream>>>(c1w, c2w, c3w, wT1, w2f, w3f);
  k_conv1    <<<dim3(512, 2), 128, 0, stream>>>(x, wT1, c1b, h1, bnpart);
  k_bnfinal2 <<<32, 256, 0, stream>>>(bnpart, 16384, 51200.f, st, st + 32);
  k_lif1b    <<<320, 256, 0, stream>>>(h1, st, st + 32, bn1g, bn1b, s1bits);

  k_conv2m   <<<512, 256, 0, stream>>>(s1bits, w2f, c2b, h2, bnpart);
  k_bnfinal2 <<<64, 256, 0, stream>>>(bnpart, 32768, 82944.f, st + 64, st + 128);
  k_lifb<9, 9><<<288, 256, 0, stream>>>(h2, st + 64, st + 128, bn2g, bn2b, s2bits, E2_ELEMS);
  prep_wff   <<<dim3(16, 8), 256, 0, stream>>>(fc1w, wff);   // h2 region now free

  k_s2T      <<<1024, 256, 0, stream>>>(s2bits, s2T);
  k_conv3m   <<<512, 256, 0, stream>>>(s2T, w3f, c3b, h3, bnpart);
  k_bnfinal2 <<<64, 256, 0, stream>>>(bnpart, 32768, 50176.f, st + 192, st + 256);
  k_lifb<7, 7><<<224, 256, 0, stream>>>(h3, st + 192, st + 256, bn3g, bn3b, s3bits, E3_ELEMS);

  k_s3T      <<<512, 256, 0, stream>>>(s3bits, s3T);
  k_fc1m     <<<dim3(16, 16), 256, 0, stream>>>(s3T, wff, f1part);
  k_fc1red_lif<<<256, 256, 0, stream>>>(f1part, fc1b, hid);
  k_fco      <<<128, 256, 0, stream>>>(hid, fcow, fcob, out);
}

// Round 13
// 248.846 us; speedup vs baseline: 1.1610x; 1.0479x over previous
//
#include <hip/hip_runtime.h>
#include <cstdint>
#include <cstddef>

#define TT 8

#define E2_ELEMS (128*64*81)      // 663,552
#define E3_ELEMS (128*64*49)      // 401,408

typedef __attribute__((ext_vector_type(8))) short short8;
typedef __attribute__((ext_vector_type(4))) float f32x4;

// ---------------- merged small weight preps: wT1 + w2frag + w3frag ----------------
__global__ void prep_all(const float* __restrict__ w1, const float* __restrict__ w2,
                         const float* __restrict__ w3, float* __restrict__ wT1,
                         __bf16* __restrict__ w2f, __bf16* __restrict__ w3f) {
  int i = blockIdx.x * 256 + threadIdx.x;
  if (i < 8192) {                                   // conv1: [ochalf][pos][16oc]
    int oc = i >> 8, pos = i & 255;
    wT1[(oc >> 4) * 4096 + pos * 16 + (oc & 15)] = w1[oc * 256 + pos];
  } else if (i < 106496) {                          // conv2 frag, exact 3-term split
    int v = i - 8192;
    int j    = v & 7;
    int oc   = (v >> 3) & 63;
    int quad = (v >> 9) & 3;
    int ksg  = (v >> 11) & 15;
    int term = v >> 15;
    int k = ksg * 32 + quad * 8 + j;
    int ci = k >> 4, kpos = k & 15;
    float w = w2[oc * 512 + ci * 16 + kpos];
    float hf = (float)(__bf16)w;
    float r1 = w - hf;
    float mf = (float)(__bf16)r1;
    float r2 = r1 - mf;
    w2f[v] = (term == 0) ? (__bf16)w : (term == 1) ? (__bf16)r1 : (__bf16)r2;
  } else if (i < 217088) {                          // conv3 frag, pos-major K=576
    int v = i - 106496;
    int j    = v & 7;
    int oc   = (v >> 3) & 63;
    int quad = (v >> 9) & 3;
    int tk   = v >> 11;
    int term = tk / 18, kstep = tk % 18;
    int k = kstep * 32 + quad * 8 + j;
    int pos = k >> 6, ci = k & 63;
    float w = w3[oc * 576 + ci * 9 + pos];
    float hf = (float)(__bf16)w;
    float r1 = w - hf;
    float mf = (float)(__bf16)r1;
    float r2 = r1 - mf;
    w3f[v] = (term == 0) ? (__bf16)w : (term == 1) ? (__bf16)r1 : (__bf16)r2;
  }
}

// ---------------- fc1 MFMA weight prep (coalesced tiled): K'=pos*64+ci ----------------
__global__ __launch_bounds__(256) void prep_wff(const float* __restrict__ w,
                                                __bf16* __restrict__ wf) {
  __shared__ float tile[12544];                     // 32 oc x 392 (8ci x 49pos)
  int oc0 = blockIdx.x * 32;                        // 16 octiles
  int ci0 = blockIdx.y * 8;                         // 8 citiles
  int tid = threadIdx.x;
  for (int f = tid; f < 12544; f += 256) {          // coalesced: 392-contig runs
    int oc_l = f / 392, r = f - oc_l * 392;
    tile[f] = w[(size_t)(oc0 + oc_l) * 3136 + ci0 * 49 + r];
  }
  __syncthreads();
  int squad = (ci0 & 31) >> 3;
  int sadd  = ci0 >> 5;
  for (int g = tid; g < 1568; g += 256) {           // 49 pos x 32 oc
    int pos = g >> 5, oc_l = g & 31;
    union { __bf16 h[8]; uint4 u; } T0, T1, T2;
    #pragma unroll
    for (int j = 0; j < 8; j++) {
      float wv = tile[oc_l * 392 + j * 49 + pos];
      float hf = (float)(__bf16)wv;
      float r1 = wv - hf;
      float mf = (float)(__bf16)r1;
      float r2 = r1 - mf;
      T0.h[j] = (__bf16)wv; T1.h[j] = (__bf16)r1; T2.h[j] = (__bf16)r2;
    }
    int s = pos * 2 + sadd;
    size_t b0 = (((size_t)s * 4 + squad) * 512 + oc0 + oc_l) * 8;
    *(uint4*)(wf + b0)           = T0.u;
    *(uint4*)(wf + b0 + 1605632) = T1.u;
    *(uint4*)(wf + b0 + 3211264) = T2.u;
  }
}

// ---------------- conv1 + fused BN partial stats ----------------
__global__ __launch_bounds__(128) void k_conv1(const float* __restrict__ x,
                                               const float* __restrict__ wT,
                                               const float* __restrict__ bias,
                                               float* __restrict__ out,
                                               float* __restrict__ pout) {
  __shared__ float xt[8064];
  int tid = threadIdx.x;
  int img = blockIdx.x >> 2;
  int q   = blockIdx.x & 3;
  int och = blockIdx.y;
  float4* dst = (float4*)xt;
  #pragma unroll
  for (int ci = 0; ci < 4; ci++) {
    const float4* s4 = (const float4*)(x + (size_t)img * 28224 + ci * 7056 + q * 1680);
    for (int i = tid; i < 504; i += 128) dst[ci * 504 + i] = s4[i];
  }
  __syncthreads();
  bool active = tid < 100;
  int oyl = tid / 20, ox = tid % 20;
  float acc[16];
  #pragma unroll
  for (int j = 0; j < 16; j++) acc[j] = 0.f;
  if (active) {
    int xb0 = oyl * 336 + ox * 4;
    const float* wh = wT + och * 4096;
    #pragma unroll 1
    for (int ci = 0; ci < 4; ci++) {
      #pragma unroll 1
      for (int ky = 0; ky < 8; ky++) {
        const float* xr = xt + ci * 2016 + xb0 + ky * 84;
        float4 xa  = *(const float4*)xr;
        float4 xbv = *(const float4*)(xr + 4);
        const float* wr = wh + (ci * 8 + ky) * 128;
        float xs[8] = {xa.x, xa.y, xa.z, xa.w, xbv.x, xbv.y, xbv.z, xbv.w};
        #pragma unroll
        for (int kx = 0; kx < 8; kx++) {
          #pragma unroll
          for (int j = 0; j < 16; j++)
            acc[j] = fmaf(xs[kx], wr[kx * 16 + j], acc[j]);
        }
      }
    }
  }
  __syncthreads();
  size_t obase = (size_t)img * 12800 + och * 6400 + (q * 5 + oyl) * 20 + ox;
  #pragma unroll
  for (int j = 0; j < 16; j++) {
    float v = 0.f;
    if (active) {
      v = acc[j] + bias[och * 16 + j];
      out[obase + j * 400] = v;
    }
    xt[j * 128 + tid] = v;
    xt[2048 + j * 128 + tid] = v * v;
  }
  __syncthreads();
  for (int off = 64; off > 0; off >>= 1) {
    if (tid < off) {
      #pragma unroll
      for (int j = 0; j < 16; j++) {
        xt[j * 128 + tid] += xt[j * 128 + tid + off];
        xt[2048 + j * 128 + tid] += xt[2048 + j * 128 + tid + off];
      }
    }
    __syncthreads();
  }
  if (tid < 16) {
    pout[(och * 16 + tid) * 512 + blockIdx.x] = xt[tid * 128];
    pout[16384 + (och * 16 + tid) * 512 + blockIdx.x] = xt[2048 + tid * 128];
  }
}

// ---------------- BN final: reduce 512 partials per channel ----------------
__global__ void k_bnfinal2(const float* __restrict__ pin, int sqoff, float n,
                           float* __restrict__ meanArr, float* __restrict__ rstdArr) {
  __shared__ float l0[256], l1[256];
  int c = blockIdx.x, tid = threadIdx.x;
  l0[tid] = pin[c * 512 + tid] + pin[c * 512 + tid + 256];
  l1[tid] = pin[sqoff + c * 512 + tid] + pin[sqoff + c * 512 + tid + 256];
  __syncthreads();
  for (int k = 128; k > 0; k >>= 1) {
    if (tid < k) { l0[tid] += l0[tid + k]; l1[tid] += l1[tid + k]; }
    __syncthreads();
  }
  if (tid == 0) {
    float m = l0[0] / n;
    float var = l1[0] / n - m * m;
    meanArr[c] = m;
    rstdArr[c] = rsqrtf(var + 1e-5f);
  }
}

// ---------------- BN + LIF stage 1 -> bit-packed spikes ----------------
__global__ void k_lif1b(const float* __restrict__ h, const float* __restrict__ mean,
                        const float* __restrict__ rstd, const float* __restrict__ g,
                        const float* __restrict__ bb, uint32_t* __restrict__ sout) {
  int idx = blockIdx.x * 256 + threadIdx.x;
  int ic = idx / 20;
  int ci = ic & 31;
  const float* hp = h + (size_t)idx * 20;
  float gm = g[ci], mm = mean[ci], rs = rstd[ci], bc = bb[ci];
  float xv[20];
  #pragma unroll
  for (int j4 = 0; j4 < 5; j4++) {
    float4 hv = ((const float4*)hp)[j4];
    xv[j4 * 4 + 0] = gm * (hv.x - mm) * rs + bc;
    xv[j4 * 4 + 1] = gm * (hv.y - mm) * rs + bc;
    xv[j4 * 4 + 2] = gm * (hv.z - mm) * rs + bc;
    xv[j4 * 4 + 3] = gm * (hv.w - mm) * rs + bc;
  }
  float v[20];
  #pragma unroll
  for (int j = 0; j < 20; j++) v[j] = 0.f;
  #pragma unroll
  for (int t = 0; t < TT; t++) {
    uint32_t w = 0;
    #pragma unroll
    for (int j = 0; j < 20; j++) {
      v[j] = v[j] + (xv[j] - v[j]) * 0.5f;
      uint32_t s = (v[j] >= 1.0f);
      w |= s << j;
      if (s) v[j] = 0.f;
    }
    sout[t * 81920 + idx] = w;
  }
}

// ---------------- conv2 via MFMA + fused BN partial stats ----------------
// block = 2 imgs, 4 waves = (img_local, oc-half). wave: mt=6 (96px), nt=2 (32oc).
__global__ __launch_bounds__(256) void k_conv2m(const uint32_t* __restrict__ s1b,
                                                const __bf16* __restrict__ wf,
                                                const float* __restrict__ bias,
                                                float* __restrict__ out,
                                                float* __restrict__ pout) {
  __shared__ uint32_t sp[1280];
  __shared__ uint4 wl4[3072];                       // 49,152 B (reused for stats)
  __bf16* wl = (__bf16*)wl4;
  int tid = threadIdx.x;
  int img0 = blockIdx.x * 2;
  {
    const uint32_t* src = s1b + (size_t)img0 * 640;
    for (int i = tid; i < 1280; i += 256) sp[i] = src[i];
  }
  int wave = tid >> 6, lane = tid & 63;
  int img_local = wave >> 1;
  int nh = wave & 1;
  int l15 = lane & 15, quad = lane >> 4;
  int ci_off = quad >> 1;
  int kyp = (quad & 1) * 2;
  int spb[6], sh[6];
  #pragma unroll
  for (int mt = 0; mt < 6; mt++) {
    int px = mt * 16 + l15;
    if (px > 80) px = 80;
    int oy = px / 9, ox = px - oy * 9;
    sh[mt]  = ox * 2;
    spb[mt] = img_local * 640 + ci_off * 20 + oy * 2 + kyp;
  }
  f32x4 acc[6][2];
  #pragma unroll
  for (int mt = 0; mt < 6; mt++)
    #pragma unroll
    for (int nt = 0; nt < 2; nt++) acc[mt][nt] = (f32x4){0.f, 0.f, 0.f, 0.f};

  for (int kc = 0; kc < 4; kc++) {
    __syncthreads();
    for (int o = tid * 8; o < 24576; o += 2048) {
      int tk = o >> 11;
      int term = tk >> 2, ksl = tk & 3;
      const __bf16* src = wf + (((term * 16 + kc * 4 + ksl)) << 11) + (o & 2047);
      *(uint4*)(wl + o) = *(const uint4*)src;
    }
    __syncthreads();
    #pragma unroll
    for (int ks = 0; ks < 4; ks++) {
      int ksg = kc * 4 + ks;
      short8 a[6];
      #pragma unroll
      for (int mt = 0; mt < 6; mt++) {
        uint32_t w0 = sp[spb[mt] + ksg * 40];
        uint32_t w1 = sp[spb[mt] + ksg * 40 + 1];
        uint32_t n0 = (w0 >> sh[mt]) & 15u;
        uint32_t n1 = (w1 >> sh[mt]) & 15u;
        union { uint32_t u[4]; short8 v; } A;
        A.u[0] = ((n0 & 1u) ? 0x3F80u : 0u) | ((n0 & 2u) ? 0x3F800000u : 0u);
        A.u[1] = ((n0 & 4u) ? 0x3F80u : 0u) | ((n0 & 8u) ? 0x3F800000u : 0u);
        A.u[2] = ((n1 & 1u) ? 0x3F80u : 0u) | ((n1 & 2u) ? 0x3F800000u : 0u);
        A.u[3] = ((n1 & 4u) ? 0x3F80u : 0u) | ((n1 & 8u) ? 0x3F800000u : 0u);
        a[mt] = A.v;
      }
      #pragma unroll
      for (int term = 0; term < 3; term++) {
        int fb = ((term * 4 + ks) << 11) + (quad << 9);
        #pragma unroll
        for (int nt = 0; nt < 2; nt++) {
          short8 b = *(const short8*)(wl + fb + ((((nh << 1) | nt) << 4) + l15) * 8);
          #pragma unroll
          for (int mt = 0; mt < 6; mt++)
            acc[mt][nt] = __builtin_amdgcn_mfma_f32_16x16x32_bf16(a[mt], b, acc[mt][nt], 0, 0, 0);
        }
      }
    }
  }
  float sl[2], sl2[2];
  #pragma unroll
  for (int nt = 0; nt < 2; nt++) {
    sl[nt] = 0.f; sl2[nt] = 0.f;
    int oc = nh * 32 + nt * 16 + l15;
    float bv = bias[oc];
    float* op = out + ((size_t)(img0 + img_local) * 64 + oc) * 81;
    #pragma unroll
    for (int mt = 0; mt < 6; mt++) {
      int pxr = mt * 16 + quad * 4;
      #pragma unroll
      for (int r = 0; r < 4; r++) {
        int px = pxr + r;
        if (px < 81) {
          float v = acc[mt][nt][r] + bv;
          op[px] = v;
          sl[nt] += v; sl2[nt] += v * v;
        }
      }
    }
  }
  __syncthreads();
  float* sred = (float*)wl4;                        // [64oc][8] + [64oc][8]
  #pragma unroll
  for (int nt = 0; nt < 2; nt++) {
    int oc = nh * 32 + nt * 16 + l15;
    int idx = oc * 8 + img_local * 4 + quad;
    sred[idx] = sl[nt];
    sred[512 + idx] = sl2[nt];
  }
  __syncthreads();
  if (tid < 64) {
    float s = 0.f, s2 = 0.f;
    #pragma unroll
    for (int k = 0; k < 8; k++) { s += sred[tid * 8 + k]; s2 += sred[512 + tid * 8 + k]; }
    pout[tid * 512 + blockIdx.x] = s;
    pout[32768 + tid * 512 + blockIdx.x] = s2;
  }
}

// ---------------- fused stage-2 BN+LIF + transpose -> s2T ----------------
// grid (128 b, 2 ci-half), 256 thr. Thread = (c_local, py) row; 288 rows (tid<32 owns 2).
__global__ __launch_bounds__(256) void k_lifb2T(const float* __restrict__ h,
                                                const float* __restrict__ mean,
                                                const float* __restrict__ rstd,
                                                const float* __restrict__ g,
                                                const float* __restrict__ bb,
                                                uint32_t* __restrict__ s2T) {
  __shared__ uint32_t sb[288];
  int b = blockIdx.x, half = blockIdx.y;
  int tid = threadIdx.x;
  int c1 = half * 32 + tid / 9, py1 = tid % 9;
  bool has2 = tid < 32;
  int r2 = tid + 256;
  int c2i = half * 32 + r2 / 9, py2 = r2 % 9;
  float gm1 = g[c1], mm1 = mean[c1], rs1 = rstd[c1], bc1 = bb[c1];
  float gm2 = 0.f, mm2 = 0.f, rs2 = 0.f, bc2 = 0.f;
  if (has2) { gm2 = g[c2i]; mm2 = mean[c2i]; rs2 = rstd[c2i]; bc2 = bb[c2i]; }
  float v1[9], v2[9];
  #pragma unroll
  for (int j = 0; j < 9; j++) { v1[j] = 0.f; v2[j] = 0.f; }
  size_t base1 = ((size_t)b * 64 + c1) * 81 + py1 * 9;
  size_t base2 = has2 ? ((size_t)b * 64 + c2i) * 81 + py2 * 9 : base1;
  #pragma unroll 1
  for (int t = 0; t < TT; t++) {
    const float* hp = h + (size_t)t * E2_ELEMS;
    uint32_t w = 0;
    #pragma unroll
    for (int j = 0; j < 9; j++) {
      float xv = gm1 * (hp[base1 + j] - mm1) * rs1 + bc1;
      v1[j] = v1[j] + (xv - v1[j]) * 0.5f;
      uint32_t s = (v1[j] >= 1.0f);
      w |= s << j;
      if (s) v1[j] = 0.f;
    }
    sb[tid] = w;
    if (has2) {
      uint32_t w2 = 0;
      #pragma unroll
      for (int j = 0; j < 9; j++) {
        float xv = gm2 * (hp[base2 + j] - mm2) * rs2 + bc2;
        v2[j] = v2[j] + (xv - v2[j]) * 0.5f;
        uint32_t s = (v2[j] >= 1.0f);
        w2 |= s << j;
        if (s) v2[j] = 0.f;
      }
      sb[r2] = w2;
    }
    __syncthreads();
    if (tid < 81) {
      int r = tid / 9, cpix = tid - r * 9;
      uint32_t wo = 0;
      #pragma unroll
      for (int ci = 0; ci < 32; ci++)
        wo |= ((sb[ci * 9 + r] >> cpix) & 1u) << ci;
      s2T[(size_t)(t * 128 + b) * 162 + tid * 2 + half] = wo;
    }
    __syncthreads();
  }
}

// ---------------- conv3 via MFMA + fused BN partial stats ----------------
// block = 2 imgs, 4 waves = (img_local, oc-half). wave: mt=4 (49px), nt=2.
__global__ __launch_bounds__(256) void k_conv3m(const uint32_t* __restrict__ s2T,
                                                const __bf16* __restrict__ wf,
                                                const float* __restrict__ bias,
                                                float* __restrict__ out,
                                                float* __restrict__ pout) {
  __shared__ uint32_t sp[324];
  __shared__ uint4 wl4[4608];                       // 73,728 B (reused for stats)
  __bf16* wl = (__bf16*)wl4;
  int tid = threadIdx.x;
  int img0 = blockIdx.x * 2;
  {
    const uint32_t* src = s2T + (size_t)img0 * 162;
    for (int i = tid; i < 324; i += 256) sp[i] = src[i];
  }
  int wave = tid >> 6, lane = tid & 63;
  int img_local = wave >> 1, nh = wave & 1;
  int l15 = lane & 15, quad = lane >> 4;
  int qsh = quad * 8;
  int base[4];
  #pragma unroll
  for (int mt = 0; mt < 4; mt++) {
    int px = mt * 16 + l15;
    if (px > 48) px = 48;
    int oy = px / 7, ox = px - oy * 7;
    base[mt] = img_local * 162 + (oy * 9 + ox) * 2;
  }
  f32x4 acc[4][2];
  #pragma unroll
  for (int mt = 0; mt < 4; mt++)
    #pragma unroll
    for (int nt = 0; nt < 2; nt++) acc[mt][nt] = (f32x4){0.f, 0.f, 0.f, 0.f};

  #pragma unroll
  for (int kc = 0; kc < 3; kc++) {
    __syncthreads();
    #pragma unroll
    for (int it = 0; it < 18; it++) {
      const __bf16* s = wf + (((it / 6) * 18 + kc * 6 + (it % 6)) << 11) + tid * 8;
      *(uint4*)(wl + (it << 11) + tid * 8) = *(const uint4*)s;
    }
    __syncthreads();
    #pragma unroll
    for (int ksl = 0; ksl < 6; ksl++) {
      int kstep = kc * 6 + ksl;
      int pos = kstep >> 1, cihalf = kstep & 1;
      int ky = pos / 3, kx = pos % 3;
      short8 a[4];
      #pragma unroll
      for (int mt = 0; mt < 4; mt++) {
        uint32_t word = sp[base[mt] + (ky * 9 + kx) * 2 + cihalf];
        uint32_t byt = (word >> qsh) & 255u;
        union { uint32_t u[4]; short8 v; } A;
        A.u[0] = ((byt & 1u)  ? 0x3F80u : 0u) | ((byt & 2u)   ? 0x3F800000u : 0u);
        A.u[1] = ((byt & 4u)  ? 0x3F80u : 0u) | ((byt & 8u)   ? 0x3F800000u : 0u);
        A.u[2] = ((byt & 16u) ? 0x3F80u : 0u) | ((byt & 32u)  ? 0x3F800000u : 0u);
        A.u[3] = ((byt & 64u) ? 0x3F80u : 0u) | ((byt & 128u) ? 0x3F800000u : 0u);
        a[mt] = A.v;
      }
      #pragma unroll
      for (int term = 0; term < 3; term++) {
        int fb = ((term * 6 + ksl) << 11) + (quad << 9);
        #pragma unroll
        for (int nt = 0; nt < 2; nt++) {
          short8 b = *(const short8*)(wl + fb + ((((nh << 1) | nt) << 4) + l15) * 8);
          #pragma unroll
          for (int mt = 0; mt < 4; mt++)
            acc[mt][nt] = __builtin_amdgcn_mfma_f32_16x16x32_bf16(a[mt], b, acc[mt][nt], 0, 0, 0);
        }
      }
    }
  }
  float sl[2], sl2[2];
  #pragma unroll
  for (int nt = 0; nt < 2; nt++) {
    sl[nt] = 0.f; sl2[nt] = 0.f;
    int oc = nh * 32 + nt * 16 + l15;
    float bv = bias[oc];
    float* op = out + ((size_t)(img0 + img_local) * 64 + oc) * 49;
    #pragma unroll
    for (int mt = 0; mt < 4; mt++) {
      int pxr = mt * 16 + quad * 4;
      #pragma unroll
      for (int r = 0; r < 4; r++) {
        int px = pxr + r;
        if (px < 49) {
          float v = acc[mt][nt][r] + bv;
          op[px] = v;
          sl[nt] += v; sl2[nt] += v * v;
        }
      }
    }
  }
  __syncthreads();
  float* sred = (float*)wl4;
  #pragma unroll
  for (int nt = 0; nt < 2; nt++) {
    int oc = nh * 32 + nt * 16 + l15;
    int idx = oc * 8 + img_local * 4 + quad;
    sred[idx] = sl[nt];
    sred[512 + idx] = sl2[nt];
  }
  __syncthreads();
  if (tid < 64) {
    float s = 0.f, s2 = 0.f;
    #pragma unroll
    for (int k = 0; k < 8; k++) { s += sred[tid * 8 + k]; s2 += sred[512 + tid * 8 + k]; }
    pout[tid * 512 + blockIdx.x] = s;
    pout[32768 + tid * 512 + blockIdx.x] = s2;
  }
}

// ---------------- fused stage-3 BN+LIF + transpose -> s3T ----------------
// grid (128 b, 2 ci-half), 256 thr. 224 rows = (c_local, py).
__global__ __launch_bounds__(256) void k_lifb3T(const float* __restrict__ h,
                                                const float* __restrict__ mean,
                                                const float* __restrict__ rstd,
                                                const float* __restrict__ g,
                                                const float* __restrict__ bb,
                                                uint32_t* __restrict__ s3T) {
  __shared__ uint32_t sb[224];
  int b = blockIdx.x, half = blockIdx.y;
  int tid = threadIdx.x;
  bool active = tid < 224;
  int row = active ? tid : 0;
  int c = half * 32 + row / 7, py = row % 7;
  float gm = g[c], mm = mean[c], rs = rstd[c], bc = bb[c];
  float v[7];
  #pragma unroll
  for (int j = 0; j < 7; j++) v[j] = 0.f;
  size_t base = ((size_t)b * 64 + c) * 49 + py * 7;
  #pragma unroll 1
  for (int t = 0; t < TT; t++) {
    const float* hp = h + (size_t)t * E3_ELEMS;
    if (active) {
      uint32_t w = 0;
      #pragma unroll
      for (int j = 0; j < 7; j++) {
        float xv = gm * (hp[base + j] - mm) * rs + bc;
        v[j] = v[j] + (xv - v[j]) * 0.5f;
        uint32_t s = (v[j] >= 1.0f);
        w |= s << j;
        if (s) v[j] = 0.f;
      }
      sb[tid] = w;
    }
    __syncthreads();
    if (tid < 49) {
      int py2 = tid / 7, px = tid - py2 * 7;
      uint32_t wo = 0;
      #pragma unroll
      for (int ci = 0; ci < 32; ci++)
        wo |= ((sb[ci * 7 + py2] >> px) & 1u) << ci;
      s3T[(size_t)(t * 128 + b) * 98 + tid * 2 + half] = wo;
    }
    __syncthreads();
  }
}

// ---------------- fc1 via MFMA ----------------
__global__ __launch_bounds__(256) void k_fc1m(const uint32_t* __restrict__ s3T,
                                              const __bf16* __restrict__ wf,
                                              float* __restrict__ part) {
  __shared__ uint32_t aS[6272];                     // 64 rows x 98 ksteps
  int tid = threadIdx.x;
  int row0 = blockIdx.x * 64;
  int oc0  = blockIdx.y * 32;
  {
    const uint32_t* src = s3T + (size_t)row0 * 98;
    for (int i = tid; i < 6272; i += 256) aS[i] = src[i];
  }
  __syncthreads();
  int wave = tid >> 6, lane = tid & 63;
  int l15 = lane & 15, quad = lane >> 4;
  int qsh = quad * 8;
  f32x4 acc[4][2];
  #pragma unroll
  for (int mt = 0; mt < 4; mt++)
    #pragma unroll
    for (int nt = 0; nt < 2; nt++) acc[mt][nt] = (f32x4){0.f, 0.f, 0.f, 0.f};
  int nIter = (wave < 2) ? 25 : 24;
  #pragma unroll 1
  for (int i = 0; i < nIter; i++) {
    int ks = i * 4 + wave;
    short8 a[4];
    #pragma unroll
    for (int mt = 0; mt < 4; mt++) {
      uint32_t word = aS[(mt * 16 + l15) * 98 + ks];
      uint32_t byt = (word >> qsh) & 255u;
      union { uint32_t u[4]; short8 v; } A;
      A.u[0] = ((byt & 1u)  ? 0x3F80u : 0u) | ((byt & 2u)   ? 0x3F800000u : 0u);
      A.u[1] = ((byt & 4u)  ? 0x3F80u : 0u) | ((byt & 8u)   ? 0x3F800000u : 0u);
      A.u[2] = ((byt & 16u) ? 0x3F80u : 0u) | ((byt & 32u)  ? 0x3F800000u : 0u);
      A.u[3] = ((byt & 64u) ? 0x3F80u : 0u) | ((byt & 128u) ? 0x3F800000u : 0u);
      a[mt] = A.v;
    }
    #pragma unroll
    for (int term = 0; term < 3; term++) {
      size_t fb = ((size_t)((term * 98 + ks) * 4 + quad) * 512 + oc0 + l15) * 8;
      #pragma unroll
      for (int nt = 0; nt < 2; nt++) {
        short8 b = *(const short8*)(wf + fb + nt * 128);
        #pragma unroll
        for (int mt = 0; mt < 4; mt++)
          acc[mt][nt] = __builtin_amdgcn_mfma_f32_16x16x32_bf16(a[mt], b, acc[mt][nt], 0, 0, 0);
      }
    }
  }
  #pragma unroll
  for (int mt = 0; mt < 4; mt++) {
    #pragma unroll
    for (int nt = 0; nt < 2; nt++) {
      int oc = oc0 + nt * 16 + l15;
      #pragma unroll
      for (int r = 0; r < 4; r++) {
        int row = row0 + mt * 16 + quad * 4 + r;
        part[(size_t)wave * 524288 + (size_t)row * 512 + oc] = acc[mt][nt][r];
      }
    }
  }
}

// ---------------- fused: 4-way reduce + bias + LIF + fco + mean over T ----------
// grid 128 (one block per b). Bit-exact replica of old fc1red_lif + fco orders.
__global__ __launch_bounds__(256) void k_fc1fco(const float* __restrict__ part,
                                                const float* __restrict__ bias,
                                                const float* __restrict__ w,
                                                const float* __restrict__ fcob,
                                                float* __restrict__ out) {
  int b = blockIdx.x, tid = threadIdx.x;
  int o0 = tid, o1 = tid + 256;
  float bv0 = bias[o0], bv1 = bias[o1];
  float v0 = 0.f, v1 = 0.f;
  float a0 = 0.f, a1 = 0.f;
  #pragma unroll
  for (int t = 0; t < TT; t++) {
    int idx0 = t * 65536 + b * 512 + o0;
    float s0 = part[idx0];
    #pragma unroll
    for (int j = 1; j < 4; j++) s0 += part[(size_t)j * 524288 + idx0];
    s0 += bv0;
    v0 = v0 + (s0 - v0) * 0.5f;
    bool sp0 = (v0 >= 1.0f);
    if (sp0) v0 = 0.f;
    int idx1 = idx0 + 256;
    float s1 = part[idx1];
    #pragma unroll
    for (int j = 1; j < 4; j++) s1 += part[(size_t)j * 524288 + idx1];
    s1 += bv1;
    v1 = v1 + (s1 - v1) * 0.5f;
    bool sp1 = (v1 >= 1.0f);
    if (sp1) v1 = 0.f;
    if (sp0) { a0 += w[o0]; a1 += w[512 + o0]; }
    if (sp1) { a0 += w[o1]; a1 += w[512 + o1]; }
  }
  __shared__ float l0[256], l1[256];
  l0[tid] = a0; l1[tid] = a1; __syncthreads();
  for (int k = 128; k > 0; k >>= 1) {
    if (tid < k) { l0[tid] += l0[tid + k]; l1[tid] += l1[tid + k]; }
    __syncthreads();
  }
  if (tid == 0) {
    out[b * 2 + 0] = l0[0] * 0.125f + fcob[0];
    out[b * 2 + 1] = l1[0] * 0.125f + fcob[1];
  }
}

extern "C" void kernel_launch(void* const* d_in, const int* in_sizes, int n_in,
                              void* d_out, int out_size, void* d_ws, size_t ws_size,
                              hipStream_t stream) {
  const float* x    = (const float*)d_in[0];
  const float* c1w  = (const float*)d_in[1];
  const float* c1b  = (const float*)d_in[2];
  const float* bn1g = (const float*)d_in[3];
  const float* bn1b = (const float*)d_in[4];
  const float* c2w  = (const float*)d_in[5];
  const float* c2b  = (const float*)d_in[6];
  const float* bn2g = (const float*)d_in[7];
  const float* bn2b = (const float*)d_in[8];
  const float* c3w  = (const float*)d_in[9];
  const float* c3b  = (const float*)d_in[10];
  const float* bn3g = (const float*)d_in[11];
  const float* bn3b = (const float*)d_in[12];
  const float* fc1w = (const float*)d_in[13];
  const float* fc1b = (const float*)d_in[14];
  const float* fcow = (const float*)d_in[15];
  const float* fcob = (const float*)d_in[16];
  float* out = (float*)d_out;

  char* ws = (char*)d_ws;
  // flat layout in the 256 MiB workspace (no overlays)
  float*    h1     = (float*)(ws + 0);                 //  6,553,600
  uint32_t* s1bits = (uint32_t*)(ws + 6553600);        //  2,621,440
  float*    h2     = (float*)(ws + 19660800);          // 21,233,664
  float*    h3     = (float*)(ws + 46202880);          // 12,845,056
  __bf16*   w2f    = (__bf16*)(ws + 60882944);         //    196,608
  __bf16*   w3f    = (__bf16*)(ws + 61079552);         //    221,184
  uint32_t* s2T    = (uint32_t*)(ws + 61300736);       //    663,552
  float*    wT1    = (float*)(ws + 62390272);          //     32,768
  float*    st     = (float*)(ws + 64880640);          //      1,280
  __bf16*   wff    = (__bf16*)(ws + 67108864);         //  9,633,792
  float*    f1part = (float*)(ws + 76742656);          //  8,388,608
  uint32_t* s3T    = (uint32_t*)(ws + 85131264);       //    401,408
  float*    bnpart = (float*)(ws + 85532672);          //    262,144

  prep_all   <<<848, 256, 0, stream>>>(c1w, c2w, c3w, wT1, w2f, w3f);
  prep_wff   <<<dim3(16, 8), 256, 0, stream>>>(fc1w, wff);
  k_conv1    <<<dim3(512, 2), 128, 0, stream>>>(x, wT1, c1b, h1, bnpart);
  k_bnfinal2 <<<32, 256, 0, stream>>>(bnpart, 16384, 51200.f, st, st + 32);
  k_lif1b    <<<320, 256, 0, stream>>>(h1, st, st + 32, bn1g, bn1b, s1bits);

  k_conv2m   <<<512, 256, 0, stream>>>(s1bits, w2f, c2b, h2, bnpart);
  k_bnfinal2 <<<64, 256, 0, stream>>>(bnpart, 32768, 82944.f, st + 64, st + 128);
  k_lifb2T   <<<dim3(128, 2), 256, 0, stream>>>(h2, st + 64, st + 128, bn2g, bn2b, s2T);

  k_conv3m   <<<512, 256, 0, stream>>>(s2T, w3f, c3b, h3, bnpart);
  k_bnfinal2 <<<64, 256, 0, stream>>>(bnpart, 32768, 50176.f, st + 192, st + 256);
  k_lifb3T   <<<dim3(128, 2), 256, 0, stream>>>(h3, st + 192, st + 256, bn3g, bn3b, s3T);

  k_fc1m     <<<dim3(16, 16), 256, 0, stream>>>(s3T, wff, f1part);
  k_fc1fco   <<<128, 256, 0, stream>>>(f1part, fc1b, fcow, fcob, out);
}